// Round 5
// baseline (76.121 us; speedup 1.0000x reference)
//
#include <hip/hip_runtime.h>

// SpikingLayer forward: first-spike times of a delayed-synapse LIF layer.
// B=128, I=512+1 bias, O=512, STEPS=200.
// R10 = R9 with phase-1 reorganized for DS-pipe issue density.
// Ledger: R7 (VALU sharing) -1.5us, R9 (occupancy 4->8 waves/SIMD) -1.0us:
// both null => phase 1 is DS-atomic-pipe-bound. Back-derivation: snn_fwd
// ~34us = 2048 wave-atomics/CU x ~40cyc; optimistic HW model says ~19cyc
// => up to ~half may be issue bubbles (atomics interleaved 1:1 with 6-op
// dependent f64 bin chains). Changes (phase-1 schedule ONLY):
//  - per g-step: compute all 8 bins + 4 weight converts into registers
//    first (8 independent f64 chains, max ILP), THEN issue the 8
//    atomicAdds as a contiguous burst (back-to-back ds_add_u32).
//  - addressing: per-lane base pointers &chargeI[bt][cg]; per-event index
//    = s*17 + k computed as (s<<4)+s (one v_lshl_add_u32), k*4 folds into
//    the ds-offset immediate.
//  - integer bin sums order-independent => bit-identical output to R9.
// Everything else identical to R9 (CSTRIDE 17, 4 blocks/CU, depth-1
// prefetch, exact f64-mul binning, wave-0 phase 2 with early exit).

#define IN_F    512
#define OUT_F   512
#define BATCH   128
#define STEPS   200
#define RES_F   1e-4f
#define COLS    16
#define CSTRIDE 17                           // 16 cols + 1; odd => banks spread
// double exp(-1e-4/5e-3) = exp(-0.02), rounded to f32 by the literal:
#define DECAY_F 0.98019867330675525f
// double (1.0 - exp(-0.02)), rounded to f32:
#define ONEMD_F 0.019801326693244747f
#define SIM_T_F 2e-2f
#define FPSCALE 8388608.0f                   // 2^23
#define INVSCALE 1.1920928955078125e-07f     // 2^-23, exact

// q = fl32(arr / 1e-4f) computed exactly: (double)arr*10000.0 is exact,
// double->float is RNE == the IEEE f32 division result, bit for bit.
// arr >= 0 always here (times >= 0, delays >= 0) so only the upper clamp.
__device__ __forceinline__ int bin_of(float arr) {
    float q = (float)((double)arr * 10000.0);
    int s = __float2int_rn(q);               // RNE == np.round half-to-even
    return s > STEPS - 1 ? STEPS - 1 : s;
}

__global__ __launch_bounds__(512, 8) void snn_fwd(
    const float* __restrict__ input_times,   // [B, IN_F]
    const float* __restrict__ weights,       // [IN_F+1, OUT_F] f32
    const float* __restrict__ delays,        // [IN_F+1, OUT_F]
    const float* __restrict__ thresholds,    // [OUT_F]
    float* __restrict__ out)                 // [B, OUT_F]
{
#pragma clang fp contract(off)
    __shared__ __align__(16) int chargeI[2][STEPS * CSTRIDE];  // 27,200 B
    __shared__ float times_s[2][IN_F];                         //  4,096 B

    const int tid  = threadIdx.x;
    const int wv   = tid >> 6;               // wave 0..7
    const int lane = tid & 63;
    const int b0    = (blockIdx.x >> 5) << 1;    // even batch of the pair
    const int otile = blockIdx.x & 31;
    const int ob    = otile << 4;                // output-column base (16-wide)

    // zero charge bins (int4) + stage both batches' input times
    {
        int4 z = make_int4(0, 0, 0, 0);
        int4* c4 = (int4*)&chargeI[0][0];
        for (int k = tid; k < (2 * STEPS * CSTRIDE) / 4; k += 512) c4[k] = z;
    }
    times_s[0][tid] = input_times[b0 * IN_F + tid];       // IN_F == blockDim
    times_s[1][tid] = input_times[(b0 + 1) * IN_F + tid];
    __syncthreads();

    // --- Phase 1: bin synapse charges for both batches ---
    // lane -> (row-offset sub 0..15, column-group cgi 0..3): one 16B load
    // covers 16 rows x 16 cols per wave-step. Wave wv owns rows
    // [64*wv, 64*wv+64) in 4 steps of 16.
    const int sub = lane >> 2;               // 0..15
    const int cgi = lane & 3;                // float4 column group
    const int cg  = cgi << 2;                // 0,4,8,12
    const float4* __restrict__ Wp = (const float4*)weights;
    const float4* __restrict__ Dp = (const float4*)delays;
    const int r0   = wv << 6;                                 // first row
    const int i0   = (r0 + sub) * (OUT_F / 4) + (ob >> 2) + cgi;
    const int gstr = 16 * (OUT_F / 4);                        // 16 rows of vec4
    int* __restrict__ base0 = &chargeI[0][cg];   // per-lane column base
    int* __restrict__ base1 = &chargeI[1][cg];

    // bias row (i=512, spike time 0): wave 7, lanes 0-31 -> (batch, col)
    if (wv == 7 && lane < 32) {
        const int bt = lane >> 4, col = lane & 15;
        float dl = delays[IN_F * OUT_F + ob + col];
        int   wt = __float2int_rn(weights[IN_F * OUT_F + ob + col] * FPSCALE);
        atomicAdd(&chargeI[bt][bin_of(dl) * CSTRIDE + col], wt);
    }

    // depth-1 ping-pong over 4 vec4-steps (8 waves/SIMD hide the rest)
    float4 wA = Wp[i0], dA = Dp[i0];
    float  tA0 = times_s[0][r0 + sub], tA1 = times_s[1][r0 + sub];

    #pragma unroll
    for (int g = 0; g < 4; ++g) {
        float4 wB = {}, dB = {};
        float  tB0 = 0.f, tB1 = 0.f;
        if (g + 1 < 4) {
            wB = Wp[i0 + (g + 1) * gstr]; dB = Dp[i0 + (g + 1) * gstr];
            tB0 = times_s[0][r0 + ((g + 1) << 4) + sub];
            tB1 = times_s[1][r0 + ((g + 1) << 4) + sub];
        }
        {
            const float* dv = (const float*)&dA;
            const float* wf = (const float*)&wA;
            // compute phase: 8 independent bin chains + 4 converts (ILP)
            int wt0, wt1, wt2, wt3;
            int a0, a1, a2, a3;              // batch-0 indices s*17
            int c0, c1, c2, c3;              // batch-1 indices s*17
            wt0 = __float2int_rn(wf[0] * FPSCALE);
            wt1 = __float2int_rn(wf[1] * FPSCALE);
            wt2 = __float2int_rn(wf[2] * FPSCALE);
            wt3 = __float2int_rn(wf[3] * FPSCALE);
            {
                int s;
                s = bin_of(tA0 + dv[0]); a0 = (s << 4) + s;
                s = bin_of(tA0 + dv[1]); a1 = (s << 4) + s;
                s = bin_of(tA0 + dv[2]); a2 = (s << 4) + s;
                s = bin_of(tA0 + dv[3]); a3 = (s << 4) + s;
                s = bin_of(tA1 + dv[0]); c0 = (s << 4) + s;
                s = bin_of(tA1 + dv[1]); c1 = (s << 4) + s;
                s = bin_of(tA1 + dv[2]); c2 = (s << 4) + s;
                s = bin_of(tA1 + dv[3]); c3 = (s << 4) + s;
            }
            // issue phase: 8 back-to-back ds_add_u32 (k*4 -> ds imm offset)
            atomicAdd(&base0[a0 + 0], wt0);
            atomicAdd(&base0[a1 + 1], wt1);
            atomicAdd(&base0[a2 + 2], wt2);
            atomicAdd(&base0[a3 + 3], wt3);
            atomicAdd(&base1[c0 + 0], wt0);
            atomicAdd(&base1[c1 + 1], wt1);
            atomicAdd(&base1[c2 + 2], wt2);
            atomicAdd(&base1[c3 + 3], wt3);
        }
        wA = wB; dA = dB; tA0 = tB0; tA1 = tB1;
    }
    __syncthreads();

    // --- Phase 2 (wave 0): exact sequential leaky integration ---
    // 32 (batch,col) pairs; lanes 32-63 mirror lanes 0-31 so the
    // __all(spiked) early-exit sees a consistent full-wave predicate.
    if (wv == 0) {
        const int bt  = (lane >> 4) & 1;
        const int col = lane & 15;
        const float thr = thresholds[ob + col];
        float syn = 0.f, mem = 0.f, spike_t = SIM_T_F;
        bool spiked = false;
        for (int t0 = 0; t0 < STEPS; t0 += 4) {
            float c[4];
            #pragma unroll
            for (int j = 0; j < 4; ++j)               // batch the ds_reads
                c[j] = (float)chargeI[bt][(t0 + j) * CSTRIDE + col] * INVSCALE;
            #pragma unroll
            for (int j = 0; j < 4; ++j) {
                float syn_n = syn * DECAY_F + c[j];               // no fma
                float mem_n = mem * DECAY_F + ONEMD_F * syn_n;    // no fma
                if (!spiked && mem_n >= thr) {
                    float denom = mem_n - mem;
                    float safe  = fabsf(denom) > 1e-12f ? denom : 1e-12f;
                    float frac  = (thr - mem) / safe;
                    frac = frac < 0.f ? 0.f : (frac > 1.f ? 1.f : frac);
                    spike_t = ((float)(t0 + j) + frac) * RES_F;
                    spiked  = true;
                }
                syn = syn_n; mem = mem_n;
            }
            if (__all(spiked)) break;        // all lanes latched (mirrored)
        }
        if (lane < 32)
            out[(b0 + bt) * OUT_F + ob + col] = spike_t;
    }
}

extern "C" void kernel_launch(void* const* d_in, const int* in_sizes, int n_in,
                              void* d_out, int out_size, void* d_ws, size_t ws_size,
                              hipStream_t stream) {
    const float* input_times = (const float*)d_in[0];   // [128, 512]
    const float* weights     = (const float*)d_in[1];   // [513, 512]
    const float* delays      = (const float*)d_in[2];   // [513, 512]
    const float* thresholds  = (const float*)d_in[3];   // [512]
    float* out = (float*)d_out;                         // [128, 512]
    (void)d_ws; (void)ws_size;                          // workspace unused

    // 64 batch-pairs x 32 column-tiles = 2048 blocks x 512 threads (8 waves)
    dim3 grid((BATCH / 2) * (OUT_F / COLS));
    snn_fwd<<<grid, 512, 0, stream>>>(input_times, weights, delays,
                                      thresholds, out);
}